// Round 3
// baseline (12.088 us; speedup 1.0000x reference)
//
#include <hip/hip_runtime.h>
#include <math.h>

// Problem constants
#define BS     256
#define IMG_H  64
#define IMG_W  64
#define OH     31
#define OW     31
#define NPOS   (OH * OW)          // 961
#define NPATCH (BS * NPOS)        // 246016 = 961 blocks * 256 threads exactly

// RY(theta) on bit `bit` of a 16-amplitude real state in registers.
__device__ __forceinline__ void ry_on(float* st, int bit, float c, float s) {
    const int m = 1 << bit;
#pragma unroll
    for (int i = 0; i < 16; ++i) {
        if (!(i & m)) {
            float a0 = st[i];
            float a1 = st[i | m];
            st[i]     = c * a0 - s * a1;
            st[i | m] = s * a0 + c * a1;
        }
    }
}

// CNOT control bit cb, target bit tb (register rename + swap, free-ish).
__device__ __forceinline__ void cnot_on(float* st, int cb, int tb) {
    const int cm = 1 << cb, tm = 1 << tb;
#pragma unroll
    for (int i = 0; i < 16; ++i) {
        if ((i & cm) && !(i & tm)) {
            float tmp = st[i];
            st[i] = st[i | tm];
            st[i | tm] = tmp;
        }
    }
}

// Prologue: build M = first 4 rows of the fixed 16x16 circuit matrix U.
// Thread t simulates U * e_t (basis column) and writes M[j][t] = st[j].
__global__ __launch_bounds__(64) void build_m_kernel(
    const float* __restrict__ wmps,   // 12 floats
    float* __restrict__ M)            // 64 floats: M[j*16 + t]
{
    const int t = threadIdx.x;
    if (t >= 16) return;

    float c[12], s[12];
#pragma unroll
    for (int i = 0; i < 12; ++i) {
        float th = 0.5f * wmps[i];
        c[i] = cosf(th);
        s[i] = sinf(th);
    }

    float st[16];
#pragma unroll
    for (int i = 0; i < 16; ++i) st[i] = 0.0f;
    st[t] = 1.0f;

#pragma unroll
    for (int l = 0; l < 2; ++l) {
#pragma unroll
        for (int blk = 0; blk < 3; ++blk) {
            const int wi = (l * 3 + blk) * 2;
            ry_on(st, 3 - blk, c[wi],     s[wi]);
            ry_on(st, 2 - blk, c[wi + 1], s[wi + 1]);
            cnot_on(st, 3 - blk, 2 - blk);
        }
    }

#pragma unroll
    for (int j = 0; j < 4; ++j) M[j * 16 + t] = st[j];
}

// Main: per patch p, out = 0.5 * (1 + |M p|^2 / |p|^2).
__global__ __launch_bounds__(256) void encoder_kernel(
    const float* __restrict__ img,    // (256,1,64,64)
    const float* __restrict__ M,      // 4x16, uniform -> scalar loads
    float* __restrict__ out)          // (256,1,961)
{
    const int idx = blockIdx.x * 256 + threadIdx.x;   // grid exactly tiles NPATCH
    const int b   = idx / NPOS;
    const int pos = idx - b * NPOS;
    const int oi  = pos / OW;
    const int oj  = pos - oi * OW;

    // Patch base: row 2*oi, col 2*oj (even column -> 8B aligned).
    const float2* base2 = (const float2*)(img + ((size_t)b * IMG_H + (size_t)(oi * 2)) * IMG_W)
                          + oj;

    float p[16];
    float n2 = 0.0f;
#pragma unroll
    for (int kh = 0; kh < 4; ++kh) {
        float2 lo = base2[kh * (IMG_W / 2)];
        float2 hi = base2[kh * (IMG_W / 2) + 1];
        p[kh * 4 + 0] = lo.x;
        p[kh * 4 + 1] = lo.y;
        p[kh * 4 + 2] = hi.x;
        p[kh * 4 + 3] = hi.y;
        n2 += lo.x * lo.x + lo.y * lo.y + hi.x * hi.x + hi.y * hi.y;
    }

    // norm==0 fallback: reference embeds e0 -> dots become M[j][0].
    if (n2 <= 0.0f) { p[0] = 1.0f; n2 = 1.0f; }

    // 4 x 16 matvec; M is wave-uniform (SGPR operands).
    float a0 = 0.0f, a1 = 0.0f, a2 = 0.0f, a3 = 0.0f;
#pragma unroll
    for (int t = 0; t < 16; ++t) {
        const float pv = p[t];
        a0 = fmaf(M[t],      pv, a0);
        a1 = fmaf(M[16 + t], pv, a1);
        a2 = fmaf(M[32 + t], pv, a2);
        a3 = fmaf(M[48 + t], pv, a3);
    }

    const float num = a0 * a0 + a1 * a1 + a2 * a2 + a3 * a3;
    out[idx] = 0.5f * (1.0f + num * __builtin_amdgcn_rcpf(n2));
}

extern "C" void kernel_launch(void* const* d_in, const int* in_sizes, int n_in,
                              void* d_out, int out_size, void* d_ws, size_t ws_size,
                              hipStream_t stream) {
    const float* img  = (const float*)d_in[0];
    const float* wmps = (const float*)d_in[1];
    float* out = (float*)d_out;
    float* M   = (float*)d_ws;   // 64 floats of scratch

    build_m_kernel<<<1, 64, 0, stream>>>(wmps, M);
    encoder_kernel<<<NPATCH / 256, 256, 0, stream>>>(img, M, out);
}

// Round 4
// 9.738 us; speedup vs baseline: 1.2414x; 1.2414x over previous
//
#include <hip/hip_runtime.h>
#include <math.h>

// Problem constants
#define BS     256
#define IMG_H  64
#define IMG_W  64
#define OH     31
#define OW     31
#define NPOS   (OH * OW)          // 961
#define NPATCH (BS * NPOS)        // 246016 = 961 blocks * 256 threads exactly

// RY(theta) on bit `bit` of a 16-amplitude real state in registers.
__device__ __forceinline__ void ry_on(float* st, int bit, float c, float s) {
    const int m = 1 << bit;
#pragma unroll
    for (int i = 0; i < 16; ++i) {
        if (!(i & m)) {
            float a0 = st[i];
            float a1 = st[i | m];
            st[i]     = c * a0 - s * a1;
            st[i | m] = s * a0 + c * a1;
        }
    }
}

// CNOT control bit cb, target bit tb (register rename + swap).
__device__ __forceinline__ void cnot_on(float* st, int cb, int tb) {
    const int cm = 1 << cb, tm = 1 << tb;
#pragma unroll
    for (int i = 0; i < 16; ++i) {
        if ((i & cm) && !(i & tm)) {
            float tmp = st[i];
            st[i] = st[i | tm];
            st[i | tm] = tmp;
        }
    }
}

// Single fused kernel:
//  phase A (threads 0-11):  c/s of the 12 half-angles -> LDS
//  phase B (threads 0-15):  simulate U * e_t, write M[j][t] (4x16) -> LDS
//  phase C (all threads):   per patch: out = 0.5*(1 + |M p|^2 / |p|^2)
__global__ __launch_bounds__(256) void encoder_kernel(
    const float* __restrict__ img,    // (256,1,64,64)
    const float* __restrict__ wmps,   // 12 floats
    float* __restrict__ out)          // (256,1,961)
{
    __shared__ float sc[12], ss[12];
    __shared__ float sM[64];          // M[j*16 + t]
    const int t = threadIdx.x;

    if (t < 12) {
        float th = 0.5f * wmps[t];
        sc[t] = cosf(th);
        ss[t] = sinf(th);
    }
    __syncthreads();

    if (t < 16) {
        float st[16];
#pragma unroll
        for (int i = 0; i < 16; ++i) st[i] = 0.0f;
        st[t] = 1.0f;
#pragma unroll
        for (int l = 0; l < 2; ++l) {
#pragma unroll
            for (int blk = 0; blk < 3; ++blk) {
                const int wi = (l * 3 + blk) * 2;
                ry_on(st, 3 - blk, sc[wi],     ss[wi]);
                ry_on(st, 2 - blk, sc[wi + 1], ss[wi + 1]);
                cnot_on(st, 3 - blk, 2 - blk);
            }
        }
#pragma unroll
        for (int j = 0; j < 4; ++j) sM[j * 16 + t] = st[j];
    }

    const int idx = blockIdx.x * 256 + t;        // grid exactly tiles NPATCH
    const int b   = idx / NPOS;
    const int pos = idx - b * NPOS;
    const int oi  = pos / OW;
    const int oj  = pos - oi * OW;

    // Patch base: row 2*oi, col 2*oj (even column -> 8B aligned).
    const float2* base2 = (const float2*)(img + ((size_t)b * IMG_H + (size_t)(oi * 2)) * IMG_W)
                          + oj;

    // Issue patch loads BEFORE the barrier so HBM/L2 latency hides under it.
    float2 r[8];
#pragma unroll
    for (int kh = 0; kh < 4; ++kh) {
        r[kh * 2]     = base2[kh * (IMG_W / 2)];
        r[kh * 2 + 1] = base2[kh * (IMG_W / 2) + 1];
    }

    __syncthreads();

    float p[16];
    float n2 = 0.0f;
#pragma unroll
    for (int i = 0; i < 8; ++i) {
        p[i * 2]     = r[i].x;
        p[i * 2 + 1] = r[i].y;
        n2 += r[i].x * r[i].x + r[i].y * r[i].y;
    }

    // norm==0 fallback: reference embeds e0.
    if (n2 <= 0.0f) { p[0] = 1.0f; n2 = 1.0f; }

    // 4x16 matvec from LDS (wave-uniform addresses -> broadcast reads).
    const float4* M4 = (const float4*)sM;
    const float4* p4 = (const float4*)p;
    float acc[4];
#pragma unroll
    for (int j = 0; j < 4; ++j) {
        float a = 0.0f;
#pragma unroll
        for (int q = 0; q < 4; ++q) {
            float4 m = M4[j * 4 + q];
            float4 v = p4[q];
            a = fmaf(m.x, v.x, a);
            a = fmaf(m.y, v.y, a);
            a = fmaf(m.z, v.z, a);
            a = fmaf(m.w, v.w, a);
        }
        acc[j] = a;
    }

    const float num = acc[0] * acc[0] + acc[1] * acc[1] + acc[2] * acc[2] + acc[3] * acc[3];
    out[idx] = 0.5f * (1.0f + num * __builtin_amdgcn_rcpf(n2));
}

extern "C" void kernel_launch(void* const* d_in, const int* in_sizes, int n_in,
                              void* d_out, int out_size, void* d_ws, size_t ws_size,
                              hipStream_t stream) {
    const float* img  = (const float*)d_in[0];
    const float* wmps = (const float*)d_in[1];
    float* out = (float*)d_out;

    encoder_kernel<<<NPATCH / 256, 256, 0, stream>>>(img, wmps, out);
}